// Round 19
// baseline (150.641 us; speedup 1.0000x reference)
//
#include <hip/hip_runtime.h>

#define N_NODES 100000
#define N_EDGES 3200000
#define IN_DIM  128
#define HID     16
#define OUTC    2

// bucket geometry: one block owns a whole bucket in k_build
#define NB     1024                   // dst-range buckets
#define SPAN   98                     // nodes per bucket (1024*98 = 100352 >= N)
#define CAP    3500                   // per-bucket capacity (mean 3136, +6.5 sigma)
#define NBLK   800                    // bucketing blocks
#define BLK_E  (N_EDGES / NBLK)       // 4000
#define VPT    4                      // scan_bb values per thread (256*4 >= 800)

// packed edge: bits 0..16 = src (100000 < 2^17), bits 17..23 = dst - bucket*SPAN (< 98)
#define PACK(s, ld)  ((unsigned)(s) | ((unsigned)(ld) << 17))
#define P_SRC(p)     ((int)((p) & 0x1FFFFu))
#define P_LDST(p)    ((int)((p) >> 17))

__device__ __forceinline__ unsigned short f2b(float f) {
    unsigned u = __float_as_uint(f);
    unsigned r = u + 0x7FFFu + ((u >> 16) & 1u);   // round-to-nearest-even
    return (unsigned short)(r >> 16);
}
__device__ __forceinline__ float b2f(unsigned short b) {
    return __uint_as_float(((unsigned)b) << 16);
}

// ---------------- K1a: per-(block,bucket) counts ----------------
__global__ __launch_bounds__(256) void k_count_bb(const int* __restrict__ dst,
                                                  int* __restrict__ bc) {
    __shared__ int h[NB];
    for (int i = threadIdx.x; i < NB; i += 256) h[i] = 0;
    __syncthreads();
    const int4* d4 = (const int4*)(dst + blockIdx.x * BLK_E);
    for (int i = threadIdx.x; i < BLK_E / 4; i += 256) {
        int4 v = d4[i];
        atomicAdd(&h[(unsigned)v.x / SPAN], 1);
        atomicAdd(&h[(unsigned)v.y / SPAN], 1);
        atomicAdd(&h[(unsigned)v.z / SPAN], 1);
        atomicAdd(&h[(unsigned)v.w / SPAN], 1);
    }
    __syncthreads();
    for (int i = threadIdx.x; i < NB; i += 256)
        bc[blockIdx.x * NB + i] = h[i];
}

// ---------------- K1b: parallel exclusive scan per bucket over NBLK blocks ----------------
__global__ __launch_bounds__(256) void k_scan_bb(int* __restrict__ bc,
                                                 int* __restrict__ bcount) {
    __shared__ int s[256];
    int b = blockIdx.x;              // bucket
    int base = threadIdx.x * VPT;
    int vals[VPT];
    int tsum = 0;
#pragma unroll
    for (int i = 0; i < VPT; ++i) {
        int t = base + i;
        vals[i] = (t < NBLK) ? bc[t * NB + b] : 0;
        tsum += vals[i];
    }
    s[threadIdx.x] = tsum;
    __syncthreads();
    for (int ofs = 1; ofs < 256; ofs <<= 1) {
        int u = (threadIdx.x >= ofs) ? s[threadIdx.x - ofs] : 0;
        __syncthreads();
        s[threadIdx.x] += u;
        __syncthreads();
    }
    int run = s[threadIdx.x] - tsum;   // exclusive prefix
#pragma unroll
    for (int i = 0; i < VPT; ++i) {
        int t = base + i;
        if (t < NBLK) { bc[t * NB + b] = run; run += vals[i]; }
    }
    if (threadIdx.x == 255) bcount[b] = s[255];
}

// ---------------- K1c: fill buckets with packed 4B edges ----------------
__global__ __launch_bounds__(256) void k_fillbkt(const int* __restrict__ src,
                                                 const int* __restrict__ dst,
                                                 const int* __restrict__ bc,
                                                 unsigned* __restrict__ bpack) {
    __shared__ int h[NB];
    __shared__ int gb[NB];
    for (int i = threadIdx.x; i < NB; i += 256) {
        h[i] = 0;
        gb[i] = i * CAP + bc[blockIdx.x * NB + i];
    }
    __syncthreads();
    const int4* d4 = (const int4*)(dst + blockIdx.x * BLK_E);
    const int4* s4 = (const int4*)(src + blockIdx.x * BLK_E);
    for (int i = threadIdx.x; i < BLK_E / 4; i += 256) {
        int4 dv = d4[i];
        int4 sv = s4[i];
        int b0 = (unsigned)dv.x / SPAN; int p0 = gb[b0] + atomicAdd(&h[b0], 1); bpack[p0] = PACK(sv.x, dv.x - b0 * SPAN);
        int b1 = (unsigned)dv.y / SPAN; int p1 = gb[b1] + atomicAdd(&h[b1], 1); bpack[p1] = PACK(sv.y, dv.y - b1 * SPAN);
        int b2 = (unsigned)dv.z / SPAN; int p2 = gb[b2] + atomicAdd(&h[b2], 1); bpack[p2] = PACK(sv.z, dv.z - b2 * SPAN);
        int b3 = (unsigned)dv.w / SPAN; int p3 = gb[b3] + atomicAdd(&h[b3], 1); bpack[p3] = PACK(sv.w, dv.w - b3 * SPAN);
    }
}

// ---------------- K2: FUSED per-bucket build: hist -> scan -> cnt/off/dinv -> csr fill ----
__global__ __launch_bounds__(256) void k_build(const unsigned* __restrict__ bpack,
                                               const int* __restrict__ bcount,
                                               int* __restrict__ cnt,
                                               int* __restrict__ off,
                                               float* __restrict__ dinv,
                                               int* __restrict__ csr) {
    __shared__ int h[SPAN];
    __shared__ int sc[256];
    __shared__ int csrBase;
    int b = blockIdx.x;
    int t = threadIdx.x;

    // exclusive prefix of bcount[0..NB) -> this bucket's csr base (4 buckets/thread)
    int vals[4];
    int tsum = 0;
#pragma unroll
    for (int i = 0; i < 4; ++i) {
        vals[i] = bcount[t * 4 + i];
        tsum += vals[i];
    }
    sc[t] = tsum;
    __syncthreads();
    for (int ofs = 1; ofs < 256; ofs <<= 1) {
        int u = (t >= ofs) ? sc[t - ofs] : 0;
        __syncthreads();
        sc[t] += u;
        __syncthreads();
    }
    if (t == (b >> 2)) {
        int run = sc[t] - tsum;
#pragma unroll
        for (int i = 0; i < 4; ++i)
            if (i < (b & 3)) run += vals[i];
        csrBase = run;
    }

    if (t < SPAN) h[t] = 0;
    __syncthreads();

    int tot = bcount[b];
    const unsigned* bp = bpack + (size_t)b * CAP;

    // phase 1: degree histogram (coalesced 4B loads, LDS atomics)
    for (int i = t; i < tot; i += 256)
        atomicAdd(&h[P_LDST(bp[i])], 1);
    __syncthreads();

    // exclusive scan of h[0..SPAN), one element per thread
    int base = b * SPAN;
    int c0 = (t < SPAN) ? h[t] : 0;
    sc[t] = c0;
    __syncthreads();
    for (int ofs = 1; ofs < 256; ofs <<= 1) {
        int u = (t >= ofs) ? sc[t - ofs] : 0;
        __syncthreads();
        sc[t] += u;
        __syncthreads();
    }
    int g0 = csrBase + sc[t] - c0;    // exclusive
    __syncthreads();                  // all hist reads done before overwrite
    if (t < SPAN) {
        int n = base + t;
        if (n < N_NODES) { cnt[n] = c0; off[n] = g0; dinv[n] = rsqrtf(1.0f + (float)c0); }
        h[t] = g0;                    // rank cursor (global csr position)
    }
    __syncthreads();

    // phase 2: place (bucket pairs L2-resident; csr window ~12.5KB, single-writer)
    for (int i = t; i < tot; i += 256) {
        unsigned e = bp[i];
        int r = atomicAdd(&h[P_LDST(e)], 1);
        csr[r] = P_SRC(e);
    }
}

// ---------------- K3: p1b(bf16) = dinv * (x @ W1) — one thread per node ----------------
__global__ __launch_bounds__(256) void k_gemm1(const float* __restrict__ x,
                                               const float* __restrict__ W1,
                                               const float* __restrict__ dinv,
                                               unsigned short* __restrict__ p1b) {
    int n = blockIdx.x * 256 + threadIdx.x;
    if (n >= N_NODES) return;

    float acc[HID];
#pragma unroll
    for (int k = 0; k < HID; ++k) acc[k] = 0.f;

    const float4* xr = (const float4*)(x + (size_t)n * IN_DIM);
#pragma unroll 4
    for (int q = 0; q < IN_DIM / 4; ++q) {
        float4 xv = xr[q];
        const float* wrow = W1 + q * 4 * HID;   // uniform -> scalar loads
#pragma unroll
        for (int k = 0; k < HID; ++k) acc[k] = fmaf(xv.x, wrow[0 * HID + k], acc[k]);
#pragma unroll
        for (int k = 0; k < HID; ++k) acc[k] = fmaf(xv.y, wrow[1 * HID + k], acc[k]);
#pragma unroll
        for (int k = 0; k < HID; ++k) acc[k] = fmaf(xv.z, wrow[2 * HID + k], acc[k]);
#pragma unroll
        for (int k = 0; k < HID; ++k) acc[k] = fmaf(xv.w, wrow[3 * HID + k], acc[k]);
    }

    float di = dinv[n];
    union { unsigned short us[HID]; uint4 v4[2]; } pk;
#pragma unroll
    for (int k = 0; k < HID; ++k) pk.us[k] = f2b(acc[k] * di);
    uint4* op = (uint4*)(p1b + (size_t)n * HID);
    op[0] = pk.v4[0];
    op[1] = pk.v4[1];
}

// ---------------- K4: node-parallel gather 1 (+relu/b1 and W2 fused) ----------------
__global__ __launch_bounds__(256) void k_gather1(const int* __restrict__ csr,
                                                 const int* __restrict__ off,
                                                 const int* __restrict__ cnt,
                                                 const unsigned short* __restrict__ p1b,
                                                 const float* __restrict__ dinv,
                                                 const float* __restrict__ b1,
                                                 const float* __restrict__ W2,
                                                 float* __restrict__ p2b) {
    int gid = blockIdx.x * 256 + threadIdx.x;
    int n = gid >> 4;
    int k = gid & 15;
    if (n >= N_NODES) return;

    int base = off[n];
    int deg = cnt[n];
    float acc = 0.f;
    int j = 0;
    for (; j + 3 < deg; j += 4) {
        int s0 = csr[base + j + 0];
        int s1 = csr[base + j + 1];
        int s2 = csr[base + j + 2];
        int s3 = csr[base + j + 3];
        float v0 = b2f(p1b[s0 * HID + k]);
        float v1 = b2f(p1b[s1 * HID + k]);
        float v2 = b2f(p1b[s2 * HID + k]);
        float v3 = b2f(p1b[s3 * HID + k]);
        acc += (v0 + v1) + (v2 + v3);
    }
    for (; j < deg; ++j) acc += b2f(p1b[csr[base + j] * HID + k]);
    acc += b2f(p1b[n * HID + k]);                // self-loop

    float di = dinv[n];
    float hval = fmaxf(fmaf(di, acc, b1[k]), 0.f);
    float hv = di * hval;
    float t0 = hv * W2[k * OUTC + 0];
    float t1 = hv * W2[k * OUTC + 1];
#pragma unroll
    for (int m = 1; m < HID; m <<= 1) {
        t0 += __shfl_xor(t0, m);
        t1 += __shfl_xor(t1, m);
    }
    if (k == 0) *(float2*)(p2b + n * OUTC) = make_float2(t0, t1);
}

// ---------------- K5: node-parallel gather 2 (+b2/log_softmax fused) ----------------
__global__ __launch_bounds__(256) void k_gather2(const int* __restrict__ csr,
                                                 const int* __restrict__ off,
                                                 const int* __restrict__ cnt,
                                                 const float* __restrict__ p2b,
                                                 const float* __restrict__ dinv,
                                                 const float* __restrict__ b2,
                                                 float* __restrict__ out) {
    int gid = blockIdx.x * 256 + threadIdx.x;
    int n = gid >> 4;
    int k = gid & 15;
    if (n >= N_NODES) return;

    int base = off[n];
    int deg = cnt[n];
    float a0 = 0.f, a1 = 0.f;
    for (int j = k; j < deg; j += 16) {
        int s = csr[base + j];
        float2 v = *(const float2*)(p2b + s * OUTC);
        a0 += v.x;
        a1 += v.y;
    }
    if (k == 0) {                                // self-loop
        float2 v = *(const float2*)(p2b + n * OUTC);
        a0 += v.x;
        a1 += v.y;
    }
#pragma unroll
    for (int m = 1; m < HID; m <<= 1) {
        a0 += __shfl_xor(a0, m);
        a1 += __shfl_xor(a1, m);
    }
    if (k == 0) {
        float di = dinv[n];
        float v0 = fmaf(di, a0, b2[0]);
        float v1 = fmaf(di, a1, b2[1]);
        float mx = fmaxf(v0, v1);
        float lse = mx + logf(expf(v0 - mx) + expf(v1 - mx));
        *(float2*)(out + n * OUTC) = make_float2(v0 - lse, v1 - lse);
    }
}

extern "C" void kernel_launch(void* const* d_in, const int* in_sizes, int n_in,
                              void* d_out, int out_size, void* d_ws, size_t ws_size,
                              hipStream_t stream) {
    const float* x  = (const float*)d_in[0];
    const int*   ei = (const int*)d_in[1];
    const float* W1 = (const float*)d_in[2];
    const float* b1 = (const float*)d_in[3];
    const float* W2 = (const float*)d_in[4];
    const float* b2 = (const float*)d_in[5];
    float* out = (float*)d_out;

    const int* src = ei;             // edge_index[0]
    const int* dst = ei + N_EDGES;   // edge_index[1]

    // workspace layout (4B elements)
    int* bc     = (int*)d_ws;                       // NBLK*NB = 819,200 (3.3 MB)
    int* bcount = bc + NBLK * NB;                   // 1024
    unsigned* bpack = (unsigned*)(((uintptr_t)(bcount + NB) + 255) & ~(uintptr_t)255); // 14.3 MB
    int* cnt    = (int*)(bpack + (size_t)NB * CAP); // 100,000
    int* off    = cnt + N_NODES;                    // 100,000
    float* dinv = (float*)(off + N_NODES);          // 100,000
    int* csr    = (int*)(dinv + N_NODES);           // 12.8 MB
    unsigned short* p1b = (unsigned short*)(csr + N_EDGES);   // 3.2 MB
    float* p2b  = (float*)(p1b + (size_t)N_NODES * HID);      // 0.8 MB

    k_count_bb <<<NBLK, 256, 0, stream>>>(dst, bc);
    k_scan_bb  <<<NB, 256, 0, stream>>>(bc, bcount);
    k_fillbkt  <<<NBLK, 256, 0, stream>>>(src, dst, bc, bpack);
    k_build    <<<NB, 256, 0, stream>>>(bpack, bcount, cnt, off, dinv, csr);
    k_gemm1    <<<(N_NODES + 255) / 256, 256, 0, stream>>>(x, W1, dinv, p1b);
    k_gather1  <<<(N_NODES * 16 + 255) / 256, 256, 0, stream>>>(csr, off, cnt, p1b, dinv, b1, W2, p2b);
    k_gather2  <<<(N_NODES * 16 + 255) / 256, 256, 0, stream>>>(csr, off, cnt, p2b, dinv, b2, out);
}

// Round 20
// 149.142 us; speedup vs baseline: 1.0101x; 1.0101x over previous
//
#include <hip/hip_runtime.h>

#define N_NODES 100000
#define N_EDGES 3200000
#define IN_DIM  128
#define HID     16
#define OUTC    2

// coarse bucket geometry (fillbkt-friendly: run = BLK_E/NB ~ 16 edges ~ 64B line)
#define NB     256                    // dst-range buckets
#define SPAN   391                    // nodes per bucket (256*391 = 100096 >= N)
#define CAP    13250                  // per-bucket capacity (mean 12500)
#define NBLK   800                    // bucketing blocks
#define BLK_E  (N_EDGES / NBLK)       // 4000
#define VPT    4                      // scan_bb values per thread (256*4 >= 800)
#define QUART  4                      // build splits per bucket
#define QSPAN  98                     // nodes per quarter (4*98 = 392 >= 391)

// packed edge: bits 0..16 = src (100000 < 2^17), bits 17..25 = dst - bucket*SPAN (< 391)
#define PACK(s, ld)  ((unsigned)(s) | ((unsigned)(ld) << 17))
#define P_SRC(p)     ((int)((p) & 0x1FFFFu))
#define P_LDST(p)    ((int)((p) >> 17))

__device__ __forceinline__ unsigned short f2b(float f) {
    unsigned u = __float_as_uint(f);
    unsigned r = u + 0x7FFFu + ((u >> 16) & 1u);   // round-to-nearest-even
    return (unsigned short)(r >> 16);
}
__device__ __forceinline__ float b2f(unsigned short b) {
    return __uint_as_float(((unsigned)b) << 16);
}

// ---------------- K1a: per-(block,bucket) counts ----------------
__global__ __launch_bounds__(256) void k_count_bb(const int* __restrict__ dst,
                                                  int* __restrict__ bc) {
    __shared__ int h[NB];
    h[threadIdx.x] = 0;
    __syncthreads();
    const int4* d4 = (const int4*)(dst + blockIdx.x * BLK_E);
    for (int i = threadIdx.x; i < BLK_E / 4; i += 256) {
        int4 v = d4[i];
        atomicAdd(&h[(unsigned)v.x / SPAN], 1);
        atomicAdd(&h[(unsigned)v.y / SPAN], 1);
        atomicAdd(&h[(unsigned)v.z / SPAN], 1);
        atomicAdd(&h[(unsigned)v.w / SPAN], 1);
    }
    __syncthreads();
    bc[blockIdx.x * NB + threadIdx.x] = h[threadIdx.x];
}

// ---------------- K1b: parallel exclusive scan per bucket over NBLK blocks ----------------
__global__ __launch_bounds__(256) void k_scan_bb(int* __restrict__ bc,
                                                 int* __restrict__ bcount) {
    __shared__ int s[256];
    int b = blockIdx.x;              // bucket
    int base = threadIdx.x * VPT;
    int vals[VPT];
    int tsum = 0;
#pragma unroll
    for (int i = 0; i < VPT; ++i) {
        int t = base + i;
        vals[i] = (t < NBLK) ? bc[t * NB + b] : 0;
        tsum += vals[i];
    }
    s[threadIdx.x] = tsum;
    __syncthreads();
    for (int ofs = 1; ofs < 256; ofs <<= 1) {
        int u = (threadIdx.x >= ofs) ? s[threadIdx.x - ofs] : 0;
        __syncthreads();
        s[threadIdx.x] += u;
        __syncthreads();
    }
    int run = s[threadIdx.x] - tsum;   // exclusive prefix
#pragma unroll
    for (int i = 0; i < VPT; ++i) {
        int t = base + i;
        if (t < NBLK) { bc[t * NB + b] = run; run += vals[i]; }
    }
    if (threadIdx.x == 255) bcount[b] = s[255];
}

// ---------------- K1c: fill buckets with packed 4B edges (64B runs/bucket) ----------------
__global__ __launch_bounds__(256) void k_fillbkt(const int* __restrict__ src,
                                                 const int* __restrict__ dst,
                                                 const int* __restrict__ bc,
                                                 unsigned* __restrict__ bpack) {
    __shared__ int h[NB];
    __shared__ int gb[NB];
    h[threadIdx.x] = 0;
    gb[threadIdx.x] = threadIdx.x * CAP + bc[blockIdx.x * NB + threadIdx.x];
    __syncthreads();
    const int4* d4 = (const int4*)(dst + blockIdx.x * BLK_E);
    const int4* s4 = (const int4*)(src + blockIdx.x * BLK_E);
    for (int i = threadIdx.x; i < BLK_E / 4; i += 256) {
        int4 dv = d4[i];
        int4 sv = s4[i];
        int b0 = (unsigned)dv.x / SPAN; int p0 = gb[b0] + atomicAdd(&h[b0], 1); bpack[p0] = PACK(sv.x, dv.x - b0 * SPAN);
        int b1 = (unsigned)dv.y / SPAN; int p1 = gb[b1] + atomicAdd(&h[b1], 1); bpack[p1] = PACK(sv.y, dv.y - b1 * SPAN);
        int b2 = (unsigned)dv.z / SPAN; int p2 = gb[b2] + atomicAdd(&h[b2], 1); bpack[p2] = PACK(sv.z, dv.z - b2 * SPAN);
        int b3 = (unsigned)dv.w / SPAN; int p3 = gb[b3] + atomicAdd(&h[b3], 1); bpack[p3] = PACK(sv.w, dv.w - b3 * SPAN);
    }
}

// ---------------- K2: quarter-split fused build: hist -> scan -> cnt/off/dinv -> csr fill ----
// grid = NB*QUART. Block (b,q) streams the WHOLE coarse bucket b (L2-resident),
// histograms the full 391-span in LDS (duplicated across quarters -> same wall
// time), but writes outputs and PLACES only its quarter's nodes/edges. The
// latency-bound scattered-store phase 2 gets 4x blocks with 1/4 serial depth.
__global__ __launch_bounds__(256) void k_build(const unsigned* __restrict__ bpack,
                                               const int* __restrict__ bcount,
                                               int* __restrict__ cnt,
                                               int* __restrict__ off,
                                               float* __restrict__ dinv,
                                               int* __restrict__ csr) {
    __shared__ int h[SPAN];
    __shared__ int sc[256];
    __shared__ int csrBase;
    int b = blockIdx.x >> 2;
    int q = blockIdx.x & 3;
    int t = threadIdx.x;
    int qlo = q * QSPAN;

    // exclusive prefix of bcount[0..NB) -> bucket b's csr base
    int bv = bcount[t];
    sc[t] = bv;
    __syncthreads();
    for (int ofs = 1; ofs < 256; ofs <<= 1) {
        int u = (t >= ofs) ? sc[t - ofs] : 0;
        __syncthreads();
        sc[t] += u;
        __syncthreads();
    }
    if (t == b) csrBase = sc[t] - bv;

    for (int i = t; i < SPAN; i += 256) h[i] = 0;
    __syncthreads();

    int tot = bcount[b];
    const unsigned* bp = bpack + (size_t)b * CAP;

    // phase 1: full-span degree histogram (coalesced 4B loads, LDS atomics)
    for (int i = t; i < tot; i += 256)
        atomicAdd(&h[P_LDST(bp[i])], 1);
    __syncthreads();

    // exclusive scan of h[0..SPAN), 2 elements per thread
    int base = b * SPAN;
    int i0 = 2 * t, i1 = 2 * t + 1;
    int c0 = (i0 < SPAN) ? h[i0] : 0;
    int c1 = (i1 < SPAN) ? h[i1] : 0;
    int ts = c0 + c1;
    __syncthreads();
    sc[t] = ts;
    __syncthreads();
    for (int ofs = 1; ofs < 256; ofs <<= 1) {
        int u = (t >= ofs) ? sc[t - ofs] : 0;
        __syncthreads();
        sc[t] += u;
        __syncthreads();
    }
    int ex = sc[t] - ts;
    int g0 = csrBase + ex;
    int g1 = g0 + c0;
    __syncthreads();                  // all hist reads done before overwrite
    // outputs + rank cursors: ONLY this block's quarter
    if (i0 < SPAN && (unsigned)(i0 - qlo) < QSPAN) {
        int n = base + i0;
        if (n < N_NODES) { cnt[n] = c0; off[n] = g0; dinv[n] = rsqrtf(1.0f + (float)c0); }
        h[i0] = g0;                   // rank cursor (global csr position)
    }
    if (i1 < SPAN && (unsigned)(i1 - qlo) < QSPAN) {
        int n = base + i1;
        if (n < N_NODES) { cnt[n] = c1; off[n] = g1; dinv[n] = rsqrtf(1.0f + (float)c1); }
        h[i1] = g1;
    }
    __syncthreads();

    // phase 2: place only this quarter's edges (~tot/4 scattered stores)
    for (int i = t; i < tot; i += 256) {
        unsigned e = bp[i];
        int ld = P_LDST(e);
        if ((unsigned)(ld - qlo) < QSPAN) {
            int r = atomicAdd(&h[ld], 1);
            csr[r] = P_SRC(e);
        }
    }
}

// ---------------- K3: p1b(bf16) = dinv * (x @ W1) — one thread per node ----------------
__global__ __launch_bounds__(256) void k_gemm1(const float* __restrict__ x,
                                               const float* __restrict__ W1,
                                               const float* __restrict__ dinv,
                                               unsigned short* __restrict__ p1b) {
    int n = blockIdx.x * 256 + threadIdx.x;
    if (n >= N_NODES) return;

    float acc[HID];
#pragma unroll
    for (int k = 0; k < HID; ++k) acc[k] = 0.f;

    const float4* xr = (const float4*)(x + (size_t)n * IN_DIM);
#pragma unroll 4
    for (int q = 0; q < IN_DIM / 4; ++q) {
        float4 xv = xr[q];
        const float* wrow = W1 + q * 4 * HID;   // uniform -> scalar loads
#pragma unroll
        for (int k = 0; k < HID; ++k) acc[k] = fmaf(xv.x, wrow[0 * HID + k], acc[k]);
#pragma unroll
        for (int k = 0; k < HID; ++k) acc[k] = fmaf(xv.y, wrow[1 * HID + k], acc[k]);
#pragma unroll
        for (int k = 0; k < HID; ++k) acc[k] = fmaf(xv.z, wrow[2 * HID + k], acc[k]);
#pragma unroll
        for (int k = 0; k < HID; ++k) acc[k] = fmaf(xv.w, wrow[3 * HID + k], acc[k]);
    }

    float di = dinv[n];
    union { unsigned short us[HID]; uint4 v4[2]; } pk;
#pragma unroll
    for (int k = 0; k < HID; ++k) pk.us[k] = f2b(acc[k] * di);
    uint4* op = (uint4*)(p1b + (size_t)n * HID);
    op[0] = pk.v4[0];
    op[1] = pk.v4[1];
}

// ---------------- K4: node-parallel gather 1 (+relu/b1 and W2 fused) ----------------
__global__ __launch_bounds__(256) void k_gather1(const int* __restrict__ csr,
                                                 const int* __restrict__ off,
                                                 const int* __restrict__ cnt,
                                                 const unsigned short* __restrict__ p1b,
                                                 const float* __restrict__ dinv,
                                                 const float* __restrict__ b1,
                                                 const float* __restrict__ W2,
                                                 float* __restrict__ p2b) {
    int gid = blockIdx.x * 256 + threadIdx.x;
    int n = gid >> 4;
    int k = gid & 15;
    if (n >= N_NODES) return;

    int base = off[n];
    int deg = cnt[n];
    float acc = 0.f;
    int j = 0;
    for (; j + 3 < deg; j += 4) {
        int s0 = csr[base + j + 0];
        int s1 = csr[base + j + 1];
        int s2 = csr[base + j + 2];
        int s3 = csr[base + j + 3];
        float v0 = b2f(p1b[s0 * HID + k]);
        float v1 = b2f(p1b[s1 * HID + k]);
        float v2 = b2f(p1b[s2 * HID + k]);
        float v3 = b2f(p1b[s3 * HID + k]);
        acc += (v0 + v1) + (v2 + v3);
    }
    for (; j < deg; ++j) acc += b2f(p1b[csr[base + j] * HID + k]);
    acc += b2f(p1b[n * HID + k]);                // self-loop

    float di = dinv[n];
    float hval = fmaxf(fmaf(di, acc, b1[k]), 0.f);
    float hv = di * hval;
    float t0 = hv * W2[k * OUTC + 0];
    float t1 = hv * W2[k * OUTC + 1];
#pragma unroll
    for (int m = 1; m < HID; m <<= 1) {
        t0 += __shfl_xor(t0, m);
        t1 += __shfl_xor(t1, m);
    }
    if (k == 0) *(float2*)(p2b + n * OUTC) = make_float2(t0, t1);
}

// ---------------- K5: node-parallel gather 2 (+b2/log_softmax fused) ----------------
__global__ __launch_bounds__(256) void k_gather2(const int* __restrict__ csr,
                                                 const int* __restrict__ off,
                                                 const int* __restrict__ cnt,
                                                 const float* __restrict__ p2b,
                                                 const float* __restrict__ dinv,
                                                 const float* __restrict__ b2,
                                                 float* __restrict__ out) {
    int gid = blockIdx.x * 256 + threadIdx.x;
    int n = gid >> 4;
    int k = gid & 15;
    if (n >= N_NODES) return;

    int base = off[n];
    int deg = cnt[n];
    float a0 = 0.f, a1 = 0.f;
    for (int j = k; j < deg; j += 16) {
        int s = csr[base + j];
        float2 v = *(const float2*)(p2b + s * OUTC);
        a0 += v.x;
        a1 += v.y;
    }
    if (k == 0) {                                // self-loop
        float2 v = *(const float2*)(p2b + n * OUTC);
        a0 += v.x;
        a1 += v.y;
    }
#pragma unroll
    for (int m = 1; m < HID; m <<= 1) {
        a0 += __shfl_xor(a0, m);
        a1 += __shfl_xor(a1, m);
    }
    if (k == 0) {
        float di = dinv[n];
        float v0 = fmaf(di, a0, b2[0]);
        float v1 = fmaf(di, a1, b2[1]);
        float mx = fmaxf(v0, v1);
        float lse = mx + logf(expf(v0 - mx) + expf(v1 - mx));
        *(float2*)(out + n * OUTC) = make_float2(v0 - lse, v1 - lse);
    }
}

extern "C" void kernel_launch(void* const* d_in, const int* in_sizes, int n_in,
                              void* d_out, int out_size, void* d_ws, size_t ws_size,
                              hipStream_t stream) {
    const float* x  = (const float*)d_in[0];
    const int*   ei = (const int*)d_in[1];
    const float* W1 = (const float*)d_in[2];
    const float* b1 = (const float*)d_in[3];
    const float* W2 = (const float*)d_in[4];
    const float* b2 = (const float*)d_in[5];
    float* out = (float*)d_out;

    const int* src = ei;             // edge_index[0]
    const int* dst = ei + N_EDGES;   // edge_index[1]

    // workspace layout (4B elements)
    int* bc     = (int*)d_ws;                       // NBLK*NB = 204,800
    int* bcount = bc + NBLK * NB;                   // 256
    unsigned* bpack = (unsigned*)(((uintptr_t)(bcount + NB) + 255) & ~(uintptr_t)255); // 13.6 MB
    int* cnt    = (int*)(bpack + (size_t)NB * CAP); // 100,000
    int* off    = cnt + N_NODES;                    // 100,000
    float* dinv = (float*)(off + N_NODES);          // 100,000
    int* csr    = (int*)(dinv + N_NODES);           // 12.8 MB
    unsigned short* p1b = (unsigned short*)(csr + N_EDGES);   // 3.2 MB
    float* p2b  = (float*)(p1b + (size_t)N_NODES * HID);      // 0.8 MB

    k_count_bb <<<NBLK, 256, 0, stream>>>(dst, bc);
    k_scan_bb  <<<NB, 256, 0, stream>>>(bc, bcount);
    k_fillbkt  <<<NBLK, 256, 0, stream>>>(src, dst, bc, bpack);
    k_build    <<<NB * QUART, 256, 0, stream>>>(bpack, bcount, cnt, off, dinv, csr);
    k_gemm1    <<<(N_NODES + 255) / 256, 256, 0, stream>>>(x, W1, dinv, p1b);
    k_gather1  <<<(N_NODES * 16 + 255) / 256, 256, 0, stream>>>(csr, off, cnt, p1b, dinv, b1, W2, p2b);
    k_gather2  <<<(N_NODES * 16 + 255) / 256, 256, 0, stream>>>(csr, off, cnt, p2b, dinv, b2, out);
}

// Round 21
// 129.326 us; speedup vs baseline: 1.1648x; 1.1532x over previous
//
#include <hip/hip_runtime.h>

#define N_NODES 100000
#define N_EDGES 3200000
#define IN_DIM  128
#define HID     16
#define OUTC    2

// bucket geometry: one 1024-thread block owns a whole bucket in k_build
#define NB     256                    // dst-range buckets
#define SPAN   391                    // nodes per bucket (256*391 = 100096 >= N)
#define CAP    13250                  // per-bucket capacity (mean 12500)
#define NBLK   1600                   // bucketing blocks
#define BLK_E  (N_EDGES / NBLK)       // 2000
#define VPT    7                      // scan_bb values per thread (256*7 >= 1600)
#define BT     1024                   // k_build block size (16 waves)

// packed edge: bits 0..16 = src (100000 < 2^17), bits 17..25 = dst - bucket*SPAN (< 391)
#define PACK(s, ld)  ((unsigned)(s) | ((unsigned)(ld) << 17))
#define P_SRC(p)     ((int)((p) & 0x1FFFFu))
#define P_LDST(p)    ((int)((p) >> 17))

__device__ __forceinline__ unsigned short f2b(float f) {
    unsigned u = __float_as_uint(f);
    unsigned r = u + 0x7FFFu + ((u >> 16) & 1u);   // round-to-nearest-even
    return (unsigned short)(r >> 16);
}
__device__ __forceinline__ float b2f(unsigned short b) {
    return __uint_as_float(((unsigned)b) << 16);
}

// ---------------- K1a: per-(block,bucket) counts ----------------
__global__ __launch_bounds__(256) void k_count_bb(const int* __restrict__ dst,
                                                  int* __restrict__ bc) {
    __shared__ int h[NB];
    h[threadIdx.x] = 0;
    __syncthreads();
    const int4* d4 = (const int4*)(dst + blockIdx.x * BLK_E);
    for (int i = threadIdx.x; i < BLK_E / 4; i += 256) {
        int4 v = d4[i];
        atomicAdd(&h[(unsigned)v.x / SPAN], 1);
        atomicAdd(&h[(unsigned)v.y / SPAN], 1);
        atomicAdd(&h[(unsigned)v.z / SPAN], 1);
        atomicAdd(&h[(unsigned)v.w / SPAN], 1);
    }
    __syncthreads();
    bc[blockIdx.x * NB + threadIdx.x] = h[threadIdx.x];
}

// ---------------- K1b: parallel exclusive scan per bucket over NBLK blocks ----------------
__global__ __launch_bounds__(256) void k_scan_bb(int* __restrict__ bc,
                                                 int* __restrict__ bcount) {
    __shared__ int s[256];
    int b = blockIdx.x;              // bucket
    int base = threadIdx.x * VPT;
    int vals[VPT];
    int tsum = 0;
#pragma unroll
    for (int i = 0; i < VPT; ++i) {
        int t = base + i;
        vals[i] = (t < NBLK) ? bc[t * NB + b] : 0;
        tsum += vals[i];
    }
    s[threadIdx.x] = tsum;
    __syncthreads();
    for (int ofs = 1; ofs < 256; ofs <<= 1) {
        int u = (threadIdx.x >= ofs) ? s[threadIdx.x - ofs] : 0;
        __syncthreads();
        s[threadIdx.x] += u;
        __syncthreads();
    }
    int run = s[threadIdx.x] - tsum;   // exclusive prefix
#pragma unroll
    for (int i = 0; i < VPT; ++i) {
        int t = base + i;
        if (t < NBLK) { bc[t * NB + b] = run; run += vals[i]; }
    }
    if (threadIdx.x == 255) bcount[b] = s[255];
}

// ---------------- K1c: fill buckets with packed 4B edges ----------------
__global__ __launch_bounds__(256) void k_fillbkt(const int* __restrict__ src,
                                                 const int* __restrict__ dst,
                                                 const int* __restrict__ bc,
                                                 unsigned* __restrict__ bpack) {
    __shared__ int h[NB];
    __shared__ int gb[NB];
    h[threadIdx.x] = 0;
    gb[threadIdx.x] = threadIdx.x * CAP + bc[blockIdx.x * NB + threadIdx.x];
    __syncthreads();
    const int4* d4 = (const int4*)(dst + blockIdx.x * BLK_E);
    const int4* s4 = (const int4*)(src + blockIdx.x * BLK_E);
    for (int i = threadIdx.x; i < BLK_E / 4; i += 256) {
        int4 dv = d4[i];
        int4 sv = s4[i];
        int b0 = (unsigned)dv.x / SPAN; int p0 = gb[b0] + atomicAdd(&h[b0], 1); bpack[p0] = PACK(sv.x, dv.x - b0 * SPAN);
        int b1 = (unsigned)dv.y / SPAN; int p1 = gb[b1] + atomicAdd(&h[b1], 1); bpack[p1] = PACK(sv.y, dv.y - b1 * SPAN);
        int b2 = (unsigned)dv.z / SPAN; int p2 = gb[b2] + atomicAdd(&h[b2], 1); bpack[p2] = PACK(sv.z, dv.z - b2 * SPAN);
        int b3 = (unsigned)dv.w / SPAN; int p3 = gb[b3] + atomicAdd(&h[b3], 1); bpack[p3] = PACK(sv.w, dv.w - b3 * SPAN);
    }
}

// ---------------- K2: FUSED whole-bucket build, 1024-thread blocks ----------------
// One 16-wave block owns one bucket: phase 1 histograms its ~12.5k edges
// (coalesced 4B loads, LDS atomics), an in-block scan over bcount[] plus the
// 391-entry span scan yields cnt/off/dinv and global rank cursors, phase 2
// re-reads the edges (bucket window L2-resident) and places into csr.
// 1024 threads cut the serial chain depth 4x vs 256 threads at no extra reads.
__global__ __launch_bounds__(BT) void k_build(const unsigned* __restrict__ bpack,
                                              const int* __restrict__ bcount,
                                              int* __restrict__ cnt,
                                              int* __restrict__ off,
                                              float* __restrict__ dinv,
                                              int* __restrict__ csr) {
    __shared__ int h[SPAN];
    __shared__ int sc[BT];
    __shared__ int csrBase;
    int b = blockIdx.x;
    int t = threadIdx.x;

    // exclusive prefix of bcount[0..NB) -> this bucket's csr base
    int bv = (t < NB) ? bcount[t] : 0;
    if (t < NB) sc[t] = bv;
    __syncthreads();
    for (int ofs = 1; ofs < NB; ofs <<= 1) {
        int u = (t >= ofs && t < NB) ? sc[t - ofs] : 0;
        __syncthreads();
        if (t < NB) sc[t] += u;
        __syncthreads();
    }
    if (t == b) csrBase = sc[t] - bv;

    for (int i = t; i < SPAN; i += BT) h[i] = 0;
    __syncthreads();

    int tot = bcount[b];
    int base = b * SPAN;
    const unsigned* bp = bpack + (size_t)b * CAP;

    // phase 1: degree histogram (~12 strided iterations)
    for (int i = t; i < tot; i += BT)
        atomicAdd(&h[P_LDST(bp[i])], 1);
    __syncthreads();

    // exclusive scan of h[0..SPAN) via Hillis-Steele over BT lanes (zeros above SPAN)
    int c0 = (t < SPAN) ? h[t] : 0;
    sc[t] = c0;
    __syncthreads();
    for (int ofs = 1; ofs < 512; ofs <<= 1) {   // 512 > SPAN covers all distances
        int u = (t >= ofs) ? sc[t - ofs] : 0;
        __syncthreads();
        sc[t] += u;
        __syncthreads();
    }
    int g0 = csrBase + sc[t] - c0;    // exclusive
    __syncthreads();                  // all hist reads done before overwrite
    if (t < SPAN) {
        int n = base + t;
        if (n < N_NODES) { cnt[n] = c0; off[n] = g0; dinv[n] = rsqrtf(1.0f + (float)c0); }
        h[t] = g0;                    // rank cursor (global csr position)
    }
    __syncthreads();

    // phase 2: place (bucket window ~50KB, single-writer, L2-resident)
    for (int i = t; i < tot; i += BT) {
        unsigned e = bp[i];
        int r = atomicAdd(&h[P_LDST(e)], 1);
        csr[r] = P_SRC(e);
    }
}

// ---------------- K3: p1b(bf16) = dinv * (x @ W1) — one thread per node ----------------
__global__ __launch_bounds__(256) void k_gemm1(const float* __restrict__ x,
                                               const float* __restrict__ W1,
                                               const float* __restrict__ dinv,
                                               unsigned short* __restrict__ p1b) {
    int n = blockIdx.x * 256 + threadIdx.x;
    if (n >= N_NODES) return;

    float acc[HID];
#pragma unroll
    for (int k = 0; k < HID; ++k) acc[k] = 0.f;

    const float4* xr = (const float4*)(x + (size_t)n * IN_DIM);
#pragma unroll 4
    for (int q = 0; q < IN_DIM / 4; ++q) {
        float4 xv = xr[q];
        const float* wrow = W1 + q * 4 * HID;   // uniform -> scalar loads
#pragma unroll
        for (int k = 0; k < HID; ++k) acc[k] = fmaf(xv.x, wrow[0 * HID + k], acc[k]);
#pragma unroll
        for (int k = 0; k < HID; ++k) acc[k] = fmaf(xv.y, wrow[1 * HID + k], acc[k]);
#pragma unroll
        for (int k = 0; k < HID; ++k) acc[k] = fmaf(xv.z, wrow[2 * HID + k], acc[k]);
#pragma unroll
        for (int k = 0; k < HID; ++k) acc[k] = fmaf(xv.w, wrow[3 * HID + k], acc[k]);
    }

    float di = dinv[n];
    union { unsigned short us[HID]; uint4 v4[2]; } pk;
#pragma unroll
    for (int k = 0; k < HID; ++k) pk.us[k] = f2b(acc[k] * di);
    uint4* op = (uint4*)(p1b + (size_t)n * HID);
    op[0] = pk.v4[0];
    op[1] = pk.v4[1];
}

// ---------------- K4: node-parallel gather 1 (+relu/b1 and W2 fused) ----------------
__global__ __launch_bounds__(256) void k_gather1(const int* __restrict__ csr,
                                                 const int* __restrict__ off,
                                                 const int* __restrict__ cnt,
                                                 const unsigned short* __restrict__ p1b,
                                                 const float* __restrict__ dinv,
                                                 const float* __restrict__ b1,
                                                 const float* __restrict__ W2,
                                                 float* __restrict__ p2b) {
    int gid = blockIdx.x * 256 + threadIdx.x;
    int n = gid >> 4;
    int k = gid & 15;
    if (n >= N_NODES) return;

    int base = off[n];
    int deg = cnt[n];
    float acc = 0.f;
    int j = 0;
    for (; j + 3 < deg; j += 4) {
        int s0 = csr[base + j + 0];
        int s1 = csr[base + j + 1];
        int s2 = csr[base + j + 2];
        int s3 = csr[base + j + 3];
        float v0 = b2f(p1b[s0 * HID + k]);
        float v1 = b2f(p1b[s1 * HID + k]);
        float v2 = b2f(p1b[s2 * HID + k]);
        float v3 = b2f(p1b[s3 * HID + k]);
        acc += (v0 + v1) + (v2 + v3);
    }
    for (; j < deg; ++j) acc += b2f(p1b[csr[base + j] * HID + k]);
    acc += b2f(p1b[n * HID + k]);                // self-loop

    float di = dinv[n];
    float hval = fmaxf(fmaf(di, acc, b1[k]), 0.f);
    float hv = di * hval;
    float t0 = hv * W2[k * OUTC + 0];
    float t1 = hv * W2[k * OUTC + 1];
#pragma unroll
    for (int m = 1; m < HID; m <<= 1) {
        t0 += __shfl_xor(t0, m);
        t1 += __shfl_xor(t1, m);
    }
    if (k == 0) *(float2*)(p2b + n * OUTC) = make_float2(t0, t1);
}

// ---------------- K5: node-parallel gather 2 (+b2/log_softmax fused) ----------------
__global__ __launch_bounds__(256) void k_gather2(const int* __restrict__ csr,
                                                 const int* __restrict__ off,
                                                 const int* __restrict__ cnt,
                                                 const float* __restrict__ p2b,
                                                 const float* __restrict__ dinv,
                                                 const float* __restrict__ b2,
                                                 float* __restrict__ out) {
    int gid = blockIdx.x * 256 + threadIdx.x;
    int n = gid >> 4;
    int k = gid & 15;
    if (n >= N_NODES) return;

    int base = off[n];
    int deg = cnt[n];
    float a0 = 0.f, a1 = 0.f;
    for (int j = k; j < deg; j += 16) {
        int s = csr[base + j];
        float2 v = *(const float2*)(p2b + s * OUTC);
        a0 += v.x;
        a1 += v.y;
    }
    if (k == 0) {                                // self-loop
        float2 v = *(const float2*)(p2b + n * OUTC);
        a0 += v.x;
        a1 += v.y;
    }
#pragma unroll
    for (int m = 1; m < HID; m <<= 1) {
        a0 += __shfl_xor(a0, m);
        a1 += __shfl_xor(a1, m);
    }
    if (k == 0) {
        float di = dinv[n];
        float v0 = fmaf(di, a0, b2[0]);
        float v1 = fmaf(di, a1, b2[1]);
        float mx = fmaxf(v0, v1);
        float lse = mx + logf(expf(v0 - mx) + expf(v1 - mx));
        *(float2*)(out + n * OUTC) = make_float2(v0 - lse, v1 - lse);
    }
}

extern "C" void kernel_launch(void* const* d_in, const int* in_sizes, int n_in,
                              void* d_out, int out_size, void* d_ws, size_t ws_size,
                              hipStream_t stream) {
    const float* x  = (const float*)d_in[0];
    const int*   ei = (const int*)d_in[1];
    const float* W1 = (const float*)d_in[2];
    const float* b1 = (const float*)d_in[3];
    const float* W2 = (const float*)d_in[4];
    const float* b2 = (const float*)d_in[5];
    float* out = (float*)d_out;

    const int* src = ei;             // edge_index[0]
    const int* dst = ei + N_EDGES;   // edge_index[1]

    // workspace layout (4B elements)
    int* bc     = (int*)d_ws;                       // NBLK*NB = 409,600 (1.6 MB)
    int* bcount = bc + NBLK * NB;                   // 256
    unsigned* bpack = (unsigned*)(((uintptr_t)(bcount + NB) + 255) & ~(uintptr_t)255); // 13.6 MB
    int* cnt    = (int*)(bpack + (size_t)NB * CAP); // 100,000
    int* off    = cnt + N_NODES;                    // 100,000
    float* dinv = (float*)(off + N_NODES);          // 100,000
    int* csr    = (int*)(dinv + N_NODES);           // 12.8 MB
    unsigned short* p1b = (unsigned short*)(csr + N_EDGES);   // 3.2 MB
    float* p2b  = (float*)(p1b + (size_t)N_NODES * HID);      // 0.8 MB

    k_count_bb <<<NBLK, 256, 0, stream>>>(dst, bc);
    k_scan_bb  <<<NB, 256, 0, stream>>>(bc, bcount);
    k_fillbkt  <<<NBLK, 256, 0, stream>>>(src, dst, bc, bpack);
    k_build    <<<NB, BT, 0, stream>>>(bpack, bcount, cnt, off, dinv, csr);
    k_gemm1    <<<(N_NODES + 255) / 256, 256, 0, stream>>>(x, W1, dinv, p1b);
    k_gather1  <<<(N_NODES * 16 + 255) / 256, 256, 0, stream>>>(csr, off, cnt, p1b, dinv, b1, W2, p2b);
    k_gather2  <<<(N_NODES * 16 + 255) / 256, 256, 0, stream>>>(csr, off, cnt, p2b, dinv, b2, out);
}

// Round 22
// 126.904 us; speedup vs baseline: 1.1870x; 1.0191x over previous
//
#include <hip/hip_runtime.h>

#define N_NODES 100000
#define N_EDGES 3200000
#define IN_DIM  128
#define HID     16
#define OUTC    2

// bucket geometry: one 1024-thread block owns a whole bucket in k_build
#define NB     256                    // dst-range buckets
#define SPAN   391                    // nodes per bucket (256*391 = 100096 >= N)
#define CAP    13250                  // per-bucket capacity (mean 12500)
#define NBLK   800                    // bucketing blocks: run = 4000/256 ~ 16 edges = 64B line
#define BLK_E  (N_EDGES / NBLK)       // 4000
#define VPT    4                      // scan_bb values per thread (256*4 >= 800)
#define BT     1024                   // k_build block size (16 waves)

// packed edge: bits 0..16 = src (100000 < 2^17), bits 17..25 = dst - bucket*SPAN (< 391)
#define PACK(s, ld)  ((unsigned)(s) | ((unsigned)(ld) << 17))
#define P_SRC(p)     ((int)((p) & 0x1FFFFu))
#define P_LDST(p)    ((int)((p) >> 17))

__device__ __forceinline__ unsigned short f2b(float f) {
    unsigned u = __float_as_uint(f);
    unsigned r = u + 0x7FFFu + ((u >> 16) & 1u);   // round-to-nearest-even
    return (unsigned short)(r >> 16);
}
__device__ __forceinline__ float b2f(unsigned short b) {
    return __uint_as_float(((unsigned)b) << 16);
}

// ---------------- K1a: per-(block,bucket) counts ----------------
__global__ __launch_bounds__(256) void k_count_bb(const int* __restrict__ dst,
                                                  int* __restrict__ bc) {
    __shared__ int h[NB];
    h[threadIdx.x] = 0;
    __syncthreads();
    const int4* d4 = (const int4*)(dst + blockIdx.x * BLK_E);
    for (int i = threadIdx.x; i < BLK_E / 4; i += 256) {
        int4 v = d4[i];
        atomicAdd(&h[(unsigned)v.x / SPAN], 1);
        atomicAdd(&h[(unsigned)v.y / SPAN], 1);
        atomicAdd(&h[(unsigned)v.z / SPAN], 1);
        atomicAdd(&h[(unsigned)v.w / SPAN], 1);
    }
    __syncthreads();
    bc[blockIdx.x * NB + threadIdx.x] = h[threadIdx.x];
}

// ---------------- K1b: parallel exclusive scan per bucket over NBLK blocks ----------------
__global__ __launch_bounds__(256) void k_scan_bb(int* __restrict__ bc,
                                                 int* __restrict__ bcount) {
    __shared__ int s[256];
    int b = blockIdx.x;              // bucket
    int base = threadIdx.x * VPT;
    int vals[VPT];
    int tsum = 0;
#pragma unroll
    for (int i = 0; i < VPT; ++i) {
        int t = base + i;
        vals[i] = (t < NBLK) ? bc[t * NB + b] : 0;
        tsum += vals[i];
    }
    s[threadIdx.x] = tsum;
    __syncthreads();
    for (int ofs = 1; ofs < 256; ofs <<= 1) {
        int u = (threadIdx.x >= ofs) ? s[threadIdx.x - ofs] : 0;
        __syncthreads();
        s[threadIdx.x] += u;
        __syncthreads();
    }
    int run = s[threadIdx.x] - tsum;   // exclusive prefix
#pragma unroll
    for (int i = 0; i < VPT; ++i) {
        int t = base + i;
        if (t < NBLK) { bc[t * NB + b] = run; run += vals[i]; }
    }
    if (threadIdx.x == 255) bcount[b] = s[255];
}

// ---------------- K1c: fill buckets with packed 4B edges (64B runs per bucket) ----------------
__global__ __launch_bounds__(256) void k_fillbkt(const int* __restrict__ src,
                                                 const int* __restrict__ dst,
                                                 const int* __restrict__ bc,
                                                 unsigned* __restrict__ bpack) {
    __shared__ int h[NB];
    __shared__ int gb[NB];
    h[threadIdx.x] = 0;
    gb[threadIdx.x] = threadIdx.x * CAP + bc[blockIdx.x * NB + threadIdx.x];
    __syncthreads();
    const int4* d4 = (const int4*)(dst + blockIdx.x * BLK_E);
    const int4* s4 = (const int4*)(src + blockIdx.x * BLK_E);
    for (int i = threadIdx.x; i < BLK_E / 4; i += 256) {
        int4 dv = d4[i];
        int4 sv = s4[i];
        int b0 = (unsigned)dv.x / SPAN; int p0 = gb[b0] + atomicAdd(&h[b0], 1); bpack[p0] = PACK(sv.x, dv.x - b0 * SPAN);
        int b1 = (unsigned)dv.y / SPAN; int p1 = gb[b1] + atomicAdd(&h[b1], 1); bpack[p1] = PACK(sv.y, dv.y - b1 * SPAN);
        int b2 = (unsigned)dv.z / SPAN; int p2 = gb[b2] + atomicAdd(&h[b2], 1); bpack[p2] = PACK(sv.z, dv.z - b2 * SPAN);
        int b3 = (unsigned)dv.w / SPAN; int p3 = gb[b3] + atomicAdd(&h[b3], 1); bpack[p3] = PACK(sv.w, dv.w - b3 * SPAN);
    }
}

// ---------------- K2: FUSED whole-bucket build, 1024-thread blocks ----------------
__global__ __launch_bounds__(BT) void k_build(const unsigned* __restrict__ bpack,
                                              const int* __restrict__ bcount,
                                              int* __restrict__ cnt,
                                              int* __restrict__ off,
                                              float* __restrict__ dinv,
                                              int* __restrict__ csr) {
    __shared__ int h[SPAN];
    __shared__ int sc[BT];
    __shared__ int csrBase;
    int b = blockIdx.x;
    int t = threadIdx.x;

    // exclusive prefix of bcount[0..NB) -> this bucket's csr base
    int bv = (t < NB) ? bcount[t] : 0;
    if (t < NB) sc[t] = bv;
    __syncthreads();
    for (int ofs = 1; ofs < NB; ofs <<= 1) {
        int u = (t >= ofs && t < NB) ? sc[t - ofs] : 0;
        __syncthreads();
        if (t < NB) sc[t] += u;
        __syncthreads();
    }
    if (t == b) csrBase = sc[t] - bv;

    for (int i = t; i < SPAN; i += BT) h[i] = 0;
    __syncthreads();

    int tot = bcount[b];
    int base = b * SPAN;
    const unsigned* bp = bpack + (size_t)b * CAP;

    // phase 1: degree histogram (~12 strided iterations)
    for (int i = t; i < tot; i += BT)
        atomicAdd(&h[P_LDST(bp[i])], 1);
    __syncthreads();

    // exclusive scan of h[0..SPAN) via Hillis-Steele over BT lanes (zeros above SPAN)
    int c0 = (t < SPAN) ? h[t] : 0;
    sc[t] = c0;
    __syncthreads();
    for (int ofs = 1; ofs < 512; ofs <<= 1) {   // 512 > SPAN covers all distances
        int u = (t >= ofs) ? sc[t - ofs] : 0;
        __syncthreads();
        sc[t] += u;
        __syncthreads();
    }
    int g0 = csrBase + sc[t] - c0;    // exclusive
    __syncthreads();                  // all hist reads done before overwrite
    if (t < SPAN) {
        int n = base + t;
        if (n < N_NODES) { cnt[n] = c0; off[n] = g0; dinv[n] = rsqrtf(1.0f + (float)c0); }
        h[t] = g0;                    // rank cursor (global csr position)
    }
    __syncthreads();

    // phase 2: place (bucket window ~50KB, single-writer, L2-resident)
    for (int i = t; i < tot; i += BT) {
        unsigned e = bp[i];
        int r = atomicAdd(&h[P_LDST(e)], 1);
        csr[r] = P_SRC(e);
    }
}

// ---------------- K3: p1b(bf16) = dinv * (x @ W1) — one thread per node ----------------
__global__ __launch_bounds__(256) void k_gemm1(const float* __restrict__ x,
                                               const float* __restrict__ W1,
                                               const float* __restrict__ dinv,
                                               unsigned short* __restrict__ p1b) {
    int n = blockIdx.x * 256 + threadIdx.x;
    if (n >= N_NODES) return;

    float acc[HID];
#pragma unroll
    for (int k = 0; k < HID; ++k) acc[k] = 0.f;

    const float4* xr = (const float4*)(x + (size_t)n * IN_DIM);
#pragma unroll 4
    for (int q = 0; q < IN_DIM / 4; ++q) {
        float4 xv = xr[q];
        const float* wrow = W1 + q * 4 * HID;   // uniform -> scalar loads
#pragma unroll
        for (int k = 0; k < HID; ++k) acc[k] = fmaf(xv.x, wrow[0 * HID + k], acc[k]);
#pragma unroll
        for (int k = 0; k < HID; ++k) acc[k] = fmaf(xv.y, wrow[1 * HID + k], acc[k]);
#pragma unroll
        for (int k = 0; k < HID; ++k) acc[k] = fmaf(xv.z, wrow[2 * HID + k], acc[k]);
#pragma unroll
        for (int k = 0; k < HID; ++k) acc[k] = fmaf(xv.w, wrow[3 * HID + k], acc[k]);
    }

    float di = dinv[n];
    union { unsigned short us[HID]; uint4 v4[2]; } pk;
#pragma unroll
    for (int k = 0; k < HID; ++k) pk.us[k] = f2b(acc[k] * di);
    uint4* op = (uint4*)(p1b + (size_t)n * HID);
    op[0] = pk.v4[0];
    op[1] = pk.v4[1];
}

// ---------------- K4: node-parallel gather 1 (+relu/b1 and W2 fused) ----------------
__global__ __launch_bounds__(256) void k_gather1(const int* __restrict__ csr,
                                                 const int* __restrict__ off,
                                                 const int* __restrict__ cnt,
                                                 const unsigned short* __restrict__ p1b,
                                                 const float* __restrict__ dinv,
                                                 const float* __restrict__ b1,
                                                 const float* __restrict__ W2,
                                                 float* __restrict__ p2b) {
    int gid = blockIdx.x * 256 + threadIdx.x;
    int n = gid >> 4;
    int k = gid & 15;
    if (n >= N_NODES) return;

    int base = off[n];
    int deg = cnt[n];
    float acc = 0.f;
    int j = 0;
    for (; j + 3 < deg; j += 4) {
        int s0 = csr[base + j + 0];
        int s1 = csr[base + j + 1];
        int s2 = csr[base + j + 2];
        int s3 = csr[base + j + 3];
        float v0 = b2f(p1b[s0 * HID + k]);
        float v1 = b2f(p1b[s1 * HID + k]);
        float v2 = b2f(p1b[s2 * HID + k]);
        float v3 = b2f(p1b[s3 * HID + k]);
        acc += (v0 + v1) + (v2 + v3);
    }
    for (; j < deg; ++j) acc += b2f(p1b[csr[base + j] * HID + k]);
    acc += b2f(p1b[n * HID + k]);                // self-loop

    float di = dinv[n];
    float hval = fmaxf(fmaf(di, acc, b1[k]), 0.f);
    float hv = di * hval;
    float t0 = hv * W2[k * OUTC + 0];
    float t1 = hv * W2[k * OUTC + 1];
#pragma unroll
    for (int m = 1; m < HID; m <<= 1) {
        t0 += __shfl_xor(t0, m);
        t1 += __shfl_xor(t1, m);
    }
    if (k == 0) *(float2*)(p2b + n * OUTC) = make_float2(t0, t1);
}

// ---------------- K5: node-parallel gather 2 (+b2/log_softmax fused) ----------------
__global__ __launch_bounds__(256) void k_gather2(const int* __restrict__ csr,
                                                 const int* __restrict__ off,
                                                 const int* __restrict__ cnt,
                                                 const float* __restrict__ p2b,
                                                 const float* __restrict__ dinv,
                                                 const float* __restrict__ b2,
                                                 float* __restrict__ out) {
    int gid = blockIdx.x * 256 + threadIdx.x;
    int n = gid >> 4;
    int k = gid & 15;
    if (n >= N_NODES) return;

    int base = off[n];
    int deg = cnt[n];
    float a0 = 0.f, a1 = 0.f;
    for (int j = k; j < deg; j += 16) {
        int s = csr[base + j];
        float2 v = *(const float2*)(p2b + s * OUTC);
        a0 += v.x;
        a1 += v.y;
    }
    if (k == 0) {                                // self-loop
        float2 v = *(const float2*)(p2b + n * OUTC);
        a0 += v.x;
        a1 += v.y;
    }
#pragma unroll
    for (int m = 1; m < HID; m <<= 1) {
        a0 += __shfl_xor(a0, m);
        a1 += __shfl_xor(a1, m);
    }
    if (k == 0) {
        float di = dinv[n];
        float v0 = fmaf(di, a0, b2[0]);
        float v1 = fmaf(di, a1, b2[1]);
        float mx = fmaxf(v0, v1);
        float lse = mx + logf(expf(v0 - mx) + expf(v1 - mx));
        *(float2*)(out + n * OUTC) = make_float2(v0 - lse, v1 - lse);
    }
}

extern "C" void kernel_launch(void* const* d_in, const int* in_sizes, int n_in,
                              void* d_out, int out_size, void* d_ws, size_t ws_size,
                              hipStream_t stream) {
    const float* x  = (const float*)d_in[0];
    const int*   ei = (const int*)d_in[1];
    const float* W1 = (const float*)d_in[2];
    const float* b1 = (const float*)d_in[3];
    const float* W2 = (const float*)d_in[4];
    const float* b2 = (const float*)d_in[5];
    float* out = (float*)d_out;

    const int* src = ei;             // edge_index[0]
    const int* dst = ei + N_EDGES;   // edge_index[1]

    // workspace layout (4B elements)
    int* bc     = (int*)d_ws;                       // NBLK*NB = 204,800
    int* bcount = bc + NBLK * NB;                   // 256
    unsigned* bpack = (unsigned*)(((uintptr_t)(bcount + NB) + 255) & ~(uintptr_t)255); // 13.6 MB
    int* cnt    = (int*)(bpack + (size_t)NB * CAP); // 100,000
    int* off    = cnt + N_NODES;                    // 100,000
    float* dinv = (float*)(off + N_NODES);          // 100,000
    int* csr    = (int*)(dinv + N_NODES);           // 12.8 MB
    unsigned short* p1b = (unsigned short*)(csr + N_EDGES);   // 3.2 MB
    float* p2b  = (float*)(p1b + (size_t)N_NODES * HID);      // 0.8 MB

    k_count_bb <<<NBLK, 256, 0, stream>>>(dst, bc);
    k_scan_bb  <<<NB, 256, 0, stream>>>(bc, bcount);
    k_fillbkt  <<<NBLK, 256, 0, stream>>>(src, dst, bc, bpack);
    k_build    <<<NB, BT, 0, stream>>>(bpack, bcount, cnt, off, dinv, csr);
    k_gemm1    <<<(N_NODES + 255) / 256, 256, 0, stream>>>(x, W1, dinv, p1b);
    k_gather1  <<<(N_NODES * 16 + 255) / 256, 256, 0, stream>>>(csr, off, cnt, p1b, dinv, b1, W2, p2b);
    k_gather2  <<<(N_NODES * 16 + 255) / 256, 256, 0, stream>>>(csr, off, cnt, p2b, dinv, b2, out);
}